// Round 3
// baseline (502.963 us; speedup 1.0000x reference)
//
#include <hip/hip_runtime.h>
#include <cstddef>

// Problem constants (match reference)
#define BATCH 4
#define SEQ   4096
#define DIM   1024
#define KCONV 4
#define EPSV  1e-6f
#define MROWS (BATCH * SEQ)      // 16384
#define CHUNK 64
#define NCHUNK (SEQ / CHUNK)     // 64

using short8v = __attribute__((ext_vector_type(8))) short;  // 8 bf16 (4 VGPRs)
using f32x4   = __attribute__((ext_vector_type(4))) float;  // MFMA acc

// bf16 helpers (RNE)
__device__ __forceinline__ unsigned short f2bf_rne(float f) {
  unsigned int u = __float_as_uint(f);
  u += 0x7FFFu + ((u >> 16) & 1u);
  return (unsigned short)(u >> 16);
}
__device__ __forceinline__ float bf2f(unsigned short h) {
  return __uint_as_float((unsigned int)h << 16);
}

// ---------------------------------------------------------------------------
// Block-wide sum reduction (256 threads = 4 waves of 64); all threads get total.
// ---------------------------------------------------------------------------
__device__ __forceinline__ float block_reduce_sum(float v) {
#pragma unroll
  for (int off = 32; off > 0; off >>= 1)
    v += __shfl_down(v, off, 64);
  __shared__ float smem[4];
  const int lane = threadIdx.x & 63;
  const int w = threadIdx.x >> 6;
  if (lane == 0) smem[w] = v;
  __syncthreads();
  return smem[0] + smem[1] + smem[2] + smem[3];
}

// ---------------------------------------------------------------------------
// splitx: fused input RMSNorm + bf16 hi/lo split.
// ---------------------------------------------------------------------------
__global__ __launch_bounds__(256) void splitx_kernel(
    const float* __restrict__ x, const float* __restrict__ norm_w,
    unsigned short* __restrict__ Xhi, unsigned short* __restrict__ Xlo) {
  const int row = blockIdx.x;
  const int c4 = threadIdx.x * 4;
  const float4 v = *reinterpret_cast<const float4*>(&x[(size_t)row * DIM + c4]);
  float ss = v.x * v.x + v.y * v.y + v.z * v.z + v.w * v.w;
  const float tot = block_reduce_sum(ss);
  const float rstd = rsqrtf(tot * (1.0f / DIM) + EPSV);
  const float4 w = *reinterpret_cast<const float4*>(&norm_w[c4]);
  const float hv[4] = {v.x * rstd * w.x, v.y * rstd * w.y,
                       v.z * rstd * w.z, v.w * rstd * w.w};
  ushort4 hh, ll;
  hh.x = f2bf_rne(hv[0]); ll.x = f2bf_rne(hv[0] - bf2f(hh.x));
  hh.y = f2bf_rne(hv[1]); ll.y = f2bf_rne(hv[1] - bf2f(hh.y));
  hh.z = f2bf_rne(hv[2]); ll.z = f2bf_rne(hv[2] - bf2f(hh.z));
  hh.w = f2bf_rne(hv[3]); ll.w = f2bf_rne(hv[3] - bf2f(hh.w));
  *reinterpret_cast<ushort4*>(&Xhi[(size_t)row * DIM + c4]) = hh;
  *reinterpret_cast<ushort4*>(&Xlo[(size_t)row * DIM + c4]) = ll;
}

// ---------------------------------------------------------------------------
// splitw: W[K][N] fp32 -> transposed bf16 hi/lo Wt[N][K]. 32x32 LDS tiles.
// ---------------------------------------------------------------------------
__global__ __launch_bounds__(256) void splitw_kernel(
    const float* __restrict__ W, unsigned short* __restrict__ Whi,
    unsigned short* __restrict__ Wlo, int K, int N) {
  __shared__ float t[32][33];
  const int n0 = blockIdx.x * 32, k0 = blockIdx.y * 32;
  const int c = threadIdx.x & 31, r = threadIdx.x >> 5;  // r: 0..7
#pragma unroll
  for (int i = 0; i < 4; ++i)
    t[r + i * 8][c] = W[(size_t)(k0 + r + i * 8) * N + n0 + c];
  __syncthreads();
#pragma unroll
  for (int i = 0; i < 4; ++i) {
    const int n = n0 + r + i * 8, k = k0 + c;
    const float v = t[c][r + i * 8];
    const unsigned short h = f2bf_rne(v);
    Whi[(size_t)n * K + k] = h;
    Wlo[(size_t)n * K + k] = f2bf_rne(v - bf2f(h));
  }
}

// ---------------------------------------------------------------------------
// bf16x3 split MFMA GEMM.  C[M][N] = (Ahi+Alo)[M][1024] * (Bhi+Blo)^T[N][1024]
// (B rows are output cols, k-contiguous, stride 1024). A row stride = lda
// (ushorts). Drops the lo*lo term.
// m97 structure: 128x128 tile, BK=32, 4 waves (2x2 quadrants), acc 4x4 f32x4.
// LDS 32 KB: Ahi/Alo/Bhi/Blo tiles of [128 rows][32 k] bf16 (8 KB each).
// Staging: global_load_lds width 16, linear LDS dest; XOR swizzle
// b ^= ((b>>7)&7)<<4 applied to SOURCE logical byte and to frag READ byte
// (involution, both sides) -> ds_read_b128 8-way bank conflict -> free 2-way.
// ---------------------------------------------------------------------------
template <bool RESID>
__global__ __launch_bounds__(256) void gemm_bf16x3_kernel(
    const unsigned short* __restrict__ Ahi, const unsigned short* __restrict__ Alo,
    const unsigned short* __restrict__ Bhi, const unsigned short* __restrict__ Blo,
    float* __restrict__ C, int N, int lda,
    const float* __restrict__ resid, const float* __restrict__ res_scale) {
  __shared__ __align__(16) unsigned short lds[16384];  // ushort offs 0/4096/8192/12288

  const int tid = threadIdx.x;
  const int lane = tid & 63;
  const int wr = tid >> 7;         // wave quadrant row (0..1)
  const int wc = (tid >> 6) & 1;   // wave quadrant col (0..1)

  // XCD-aware block swizzle (nwg divisible by 8 for both GEMMs here)
  const int nwg = gridDim.x * gridDim.y;
  int id = blockIdx.y * gridDim.x + blockIdx.x;
  id = (id & 7) * (nwg >> 3) + (id >> 3);
  const int bx = id % gridDim.x;
  const int by = id / gridDim.x;
  const int bm = by * 128;
  const int bn = bx * 128;

  // Staging: 8 x 16B per thread per K-step. Linear LDS byte o = tid*16+i*4096;
  // within-tile offset ot = o&8191; source logical byte b = ot^swz(ot).
  const unsigned short* pg[8];
  unsigned int lofs[8];
#pragma unroll
  for (int i = 0; i < 8; ++i) {
    const int o = tid * 16 + i * 4096;
    const int ot = o & 8191;
    const int b = ot ^ (((ot >> 7) & 7) << 4);
    const int r = b >> 6;             // tile row 0..127
    const int ck = (b & 63) >> 1;     // k offset (ushorts): 0,8,16,24
    const unsigned short* base = (i < 2) ? Ahi : (i < 4) ? Alo
                               : (i < 6) ? Bhi : Blo;
    const int stride = (i < 4) ? lda : 1024;
    const int rowg = ((i >> 1) < 2 ? bm : bn) + r;
    pg[i] = base + (size_t)rowg * stride + ck;
    lofs[i] = (unsigned int)(o >> 1);
  }

  // Fragment read offsets (ushort idx), swizzled; lo tiles at +4096 ushorts.
  unsigned int aoff[4], boff[4];
#pragma unroll
  for (int i = 0; i < 4; ++i) {
    int ba = (wr * 64 + i * 16 + (lane & 15)) * 64 + (lane >> 4) * 16;
    ba ^= ((ba >> 7) & 7) << 4;
    aoff[i] = (unsigned int)(ba >> 1);
    int bb = (wc * 64 + i * 16 + (lane & 15)) * 64 + (lane >> 4) * 16;
    bb ^= ((bb >> 7) & 7) << 4;
    boff[i] = (unsigned int)(bb >> 1) + 8192;
  }

  f32x4 acc[4][4];
#pragma unroll
  for (int mi = 0; mi < 4; ++mi)
#pragma unroll
    for (int ni = 0; ni < 4; ++ni) {
      acc[mi][ni][0] = 0.f; acc[mi][ni][1] = 0.f;
      acc[mi][ni][2] = 0.f; acc[mi][ni][3] = 0.f;
    }

  for (int k0 = 0; k0 < 1024; k0 += 32) {
#pragma unroll
    for (int i = 0; i < 8; ++i)
      __builtin_amdgcn_global_load_lds(
          (const __attribute__((address_space(1))) void*)(pg[i] + k0),
          (__attribute__((address_space(3))) void*)(&lds[lofs[i]]), 16, 0, 0);
    __syncthreads();  // compiler drains vmcnt before s_barrier

    short8v bh[4], bl[4];
#pragma unroll
    for (int ni = 0; ni < 4; ++ni) {
      bh[ni] = *reinterpret_cast<const short8v*>(&lds[boff[ni]]);
      bl[ni] = *reinterpret_cast<const short8v*>(&lds[boff[ni] + 4096]);
    }
#pragma unroll
    for (int mi = 0; mi < 4; ++mi) {
      const short8v ah = *reinterpret_cast<const short8v*>(&lds[aoff[mi]]);
      const short8v al = *reinterpret_cast<const short8v*>(&lds[aoff[mi] + 4096]);
#pragma unroll
      for (int ni = 0; ni < 4; ++ni) {
        acc[mi][ni] = __builtin_amdgcn_mfma_f32_16x16x32_bf16(ah, bh[ni], acc[mi][ni], 0, 0, 0);
        acc[mi][ni] = __builtin_amdgcn_mfma_f32_16x16x32_bf16(ah, bl[ni], acc[mi][ni], 0, 0, 0);
        acc[mi][ni] = __builtin_amdgcn_mfma_f32_16x16x32_bf16(al, bh[ni], acc[mi][ni], 0, 0, 0);
      }
    }
    __syncthreads();
  }

  // Epilogue: C/D layout col=lane&15, row=(lane>>4)*4+reg (verified m89/m91).
  const float rscale = RESID ? res_scale[0] : 0.0f;
#pragma unroll
  for (int mi = 0; mi < 4; ++mi) {
    const int row0 = bm + wr * 64 + mi * 16 + (lane >> 4) * 4;
#pragma unroll
    for (int ni = 0; ni < 4; ++ni) {
      const int col = bn + wc * 64 + ni * 16 + (lane & 15);
#pragma unroll
      for (int r = 0; r < 4; ++r) {
        const size_t idx = (size_t)(row0 + r) * N + col;
        float v = acc[mi][ni][r];
        if constexpr (RESID) v = fmaf(resid[idx], rscale, v);
        C[idx] = v;
      }
    }
  }
}

// ---------------------------------------------------------------------------
// Phase A: depthwise causal conv(K=4) + bias + silu, then LOCAL scan within
// each chunk. Grid: (DIM/256, NCHUNK, BATCH).
// ---------------------------------------------------------------------------
__global__ __launch_bounds__(256) void phaseA_kernel(
    const float* __restrict__ xz, const float* __restrict__ conv_w,
    const float* __restrict__ conv_b, const float* __restrict__ decay,
    float* __restrict__ hs, float* __restrict__ fbuf) {
  const int d = blockIdx.x * 256 + threadIdx.x;
  const int c = blockIdx.y;
  const int b = blockIdx.z;
  const int t0 = c * CHUNK;

  const float w0 = conv_w[d * KCONV + 0];
  const float w1 = conv_w[d * KCONV + 1];
  const float w2 = conv_w[d * KCONV + 2];
  const float w3 = conv_w[d * KCONV + 3];
  const float cb = conv_b[d];
  const float a = 1.0f / (1.0f + expf(-decay[d]));

  const size_t rowbase = ((size_t)b * SEQ + t0) * (2 * DIM) + d;
  float xm1 = 0.f, xm2 = 0.f, xm3 = 0.f;
  if (t0 >= 1) xm1 = xz[rowbase - 1 * (size_t)(2 * DIM)];
  if (t0 >= 2) xm2 = xz[rowbase - 2 * (size_t)(2 * DIM)];
  if (t0 >= 3) xm3 = xz[rowbase - 3 * (size_t)(2 * DIM)];

  float h = 0.f;
  size_t src = rowbase;
  size_t dst = ((size_t)b * SEQ + t0) * DIM + d;
#pragma unroll 4
  for (int t = 0; t < CHUNK; ++t) {
    const float cur = xz[src];
    const float conv =
        fmaf(w0, xm3, fmaf(w1, xm2, fmaf(w2, xm1, fmaf(w3, cur, cb))));
    const float u = conv / (1.0f + expf(-conv));  // silu
    h = fmaf(a, h, u);
    hs[dst] = h;
    xm3 = xm2; xm2 = xm1; xm1 = cur;
    src += 2 * DIM;
    dst += DIM;
  }
  fbuf[((size_t)b * NCHUNK + c) * DIM + d] = h;
}

// ---------------------------------------------------------------------------
// Phase B: sequential carry propagation across chunks. Grid: (DIM/256, BATCH).
// ---------------------------------------------------------------------------
__global__ __launch_bounds__(256) void phaseB_kernel(
    const float* __restrict__ decay, const float* __restrict__ fbuf,
    float* __restrict__ cbuf) {
  const int d = blockIdx.x * 256 + threadIdx.x;
  const int b = blockIdx.y;
  const float a = 1.0f / (1.0f + expf(-decay[d]));
  const float aL = exp2f((float)CHUNK * __log2f(a));
  float carry = 0.f;
  for (int c = 0; c < NCHUNK; ++c) {
    const size_t idx = ((size_t)b * NCHUNK + c) * DIM + d;
    cbuf[idx] = carry;
    carry = fmaf(aL, carry, fbuf[idx]);
  }
}

// ---------------------------------------------------------------------------
// Phase C: h_full = hs_local + a^(j+1)*carry; y = rmsnorm(h_full, gate_w) *
// silu(z), emitted as bf16 hi/lo OVERLAID into the dead xb half of this row
// of xz (yh at row byte 0..2048, yl at 2048..4096; z half untouched).
// ---------------------------------------------------------------------------
__global__ __launch_bounds__(256) void phaseC_kernel(
    const float* __restrict__ xz, const float* __restrict__ hs,
    const float* __restrict__ cbuf, const float* __restrict__ decay,
    const float* __restrict__ gate_w, unsigned short* __restrict__ Yhi,
    unsigned short* __restrict__ Ylo) {
  const int row = blockIdx.x;          // b*SEQ + t
  const int b = row >> 12;             // SEQ = 4096
  const int t = row & (SEQ - 1);
  const int c = t / CHUNK;
  const float e = (float)(t - c * CHUNK + 1);

  float hv[4];
  float ss = 0.f;
#pragma unroll
  for (int i = 0; i < 4; ++i) {
    const int d = threadIdx.x + i * 256;
    const float a = 1.0f / (1.0f + expf(-decay[d]));
    const float ae = exp2f(e * __log2f(a));
    const float carry = cbuf[((size_t)b * NCHUNK + c) * DIM + d];
    const float v = fmaf(ae, carry, hs[(size_t)row * DIM + d]);
    hv[i] = v;
    ss = fmaf(v, v, ss);
  }
  const float tot = block_reduce_sum(ss);
  const float rstd = rsqrtf(tot * (1.0f / DIM) + EPSV);
#pragma unroll
  for (int i = 0; i < 4; ++i) {
    const int d = threadIdx.x + i * 256;
    const float zv = xz[(size_t)row * (2 * DIM) + DIM + d];
    const float sz = zv / (1.0f + expf(-zv));  // silu(z)
    const float vv = hv[i] * rstd * gate_w[d] * sz;
    const unsigned short h = f2bf_rne(vv);
    Yhi[(size_t)row * 4096 + d] = h;       // row stride 4096 ushorts (overlay)
    Ylo[(size_t)row * 4096 + d] = f2bf_rne(vv - bf2f(h));
  }
}

// ---------------------------------------------------------------------------
extern "C" void kernel_launch(void* const* d_in, const int* in_sizes, int n_in,
                              void* d_out, int out_size, void* d_ws,
                              size_t ws_size, hipStream_t stream) {
  const float* x = (const float*)d_in[0];
  const float* norm_w = (const float*)d_in[1];
  const float* in_w = (const float*)d_in[2];
  const float* conv_w = (const float*)d_in[3];
  const float* conv_b = (const float*)d_in[4];
  const float* decay = (const float*)d_in[5];
  const float* gate_w = (const float*)d_in[6];
  const float* out_w = (const float*)d_in[7];
  const float* res_scale = (const float*)d_in[8];
  float* out = (float*)d_out;

  // Workspace layout (bytes), peak 216,006,656 B (~206 MiB) via overlays:
  //  [0, 134.2M)      xz fp32 [M][2048]; after phaseA the xb half is dead and
  //                   phaseC overlays y_hi/y_lo (bf16) into it per-row.
  //  [134.2M, 201.3M) x_hi|x_lo (bf16) for GEMM1; dead after GEMM1, then
  //                   phaseA overlays hs fp32 [M][1024] here.
  //  [201.3M, 213.9M) w1hi|w1lo|w2hi|w2lo (bf16, transposed)
  //  [213.9M, 216.0M) fbuf | cbuf
  const size_t NEEDED = 216006656;
  if (ws_size < NEEDED) return;  // clean diagnostic fail instead of OOB fault

  char* w8 = (char*)d_ws;
  float* xz = (float*)(w8);
  unsigned short* xhi = (unsigned short*)(w8 + 134217728);
  unsigned short* xlo = (unsigned short*)(w8 + 167772160);
  float* hs = (float*)(w8 + 134217728);                       // overlays xhi/xlo
  unsigned short* yhi = (unsigned short*)(w8);                // overlays xz xb half
  unsigned short* ylo = (unsigned short*)(w8) + 1024;         //   (row stride 4096)
  unsigned short* w1hi = (unsigned short*)(w8 + 201326592);
  unsigned short* w1lo = (unsigned short*)(w8 + 205520896);
  unsigned short* w2hi = (unsigned short*)(w8 + 209715200);
  unsigned short* w2lo = (unsigned short*)(w8 + 211812352);
  float* fbuf = (float*)(w8 + 213909504);
  float* cbuf = (float*)(w8 + 214958080);

  // 1. fused RMSNorm + bf16 split of x
  splitx_kernel<<<MROWS, 256, 0, stream>>>(x, norm_w, xhi, xlo);

  // 2. weight transpose+split (Wt[N][K] bf16 hi/lo)
  splitw_kernel<<<dim3((2 * DIM) / 32, DIM / 32), 256, 0, stream>>>(
      in_w, w1hi, w1lo, DIM, 2 * DIM);
  splitw_kernel<<<dim3(DIM / 32, DIM / 32), 256, 0, stream>>>(
      out_w, w2hi, w2lo, DIM, DIM);

  // 3. GEMM1: xz = norm(x) @ in_w   [16384 x 2048], A stride 1024
  gemm_bf16x3_kernel<false><<<dim3((2 * DIM) / 128, MROWS / 128), 256, 0, stream>>>(
      xhi, xlo, w1hi, w1lo, xz, 2 * DIM, 1024, nullptr, nullptr);

  // 4. conv + silu + local scan (reads xz xb; writes hs over dead xhi/xlo)
  phaseA_kernel<<<dim3(DIM / 256, NCHUNK, BATCH), 256, 0, stream>>>(
      xz, conv_w, conv_b, decay, hs, fbuf);

  // 5. chunk carry propagation
  phaseB_kernel<<<dim3(DIM / 256, BATCH), 256, 0, stream>>>(decay, fbuf, cbuf);

  // 6. carry injection + gated rmsnorm * silu(z) -> y bf16 overlay into xz
  phaseC_kernel<<<MROWS, 256, 0, stream>>>(xz, hs, cbuf, decay, gate_w, yhi, ylo);

  // 7. GEMM2: out = x * res_scale + y @ out_w  [16384 x 1024], A stride 4096
  gemm_bf16x3_kernel<true><<<dim3(DIM / 128, MROWS / 128), 256, 0, stream>>>(
      yhi, ylo, w2hi, w2lo, out, DIM, 4096, x, res_scale);
}

// Round 4
// 421.282 us; speedup vs baseline: 1.1939x; 1.1939x over previous
//
#include <hip/hip_runtime.h>
#include <cstddef>

// Problem constants (match reference)
#define BATCH 4
#define SEQ   4096
#define DIM   1024
#define KCONV 4
#define EPSV  1e-6f
#define MROWS (BATCH * SEQ)      // 16384
#define CHUNK 32
#define NCHUNK (SEQ / CHUNK)     // 128

using short8v = __attribute__((ext_vector_type(8))) short;  // 8 bf16 (4 VGPRs)
using f32x4   = __attribute__((ext_vector_type(4))) float;  // MFMA acc

// bf16 helpers (RNE)
__device__ __forceinline__ unsigned short f2bf_rne(float f) {
  unsigned int u = __float_as_uint(f);
  u += 0x7FFFu + ((u >> 16) & 1u);
  return (unsigned short)(u >> 16);
}
__device__ __forceinline__ float bf2f(unsigned short h) {
  return __uint_as_float((unsigned int)h << 16);
}

// Full-wave (64-lane) sum reduction; all lanes get the total.
__device__ __forceinline__ float wave_reduce_sum(float v) {
#pragma unroll
  for (int off = 32; off > 0; off >>= 1)
    v += __shfl_xor(v, off, 64);
  return v;
}

// ---------------------------------------------------------------------------
// splitx: fused input RMSNorm + bf16 hi/lo split. One WAVE per row (no
// barriers); block = 4 waves = 4 rows. Each lane handles 16 elements.
// ---------------------------------------------------------------------------
__global__ __launch_bounds__(256) void splitx_kernel(
    const float* __restrict__ x, const float* __restrict__ norm_w,
    unsigned short* __restrict__ Xhi, unsigned short* __restrict__ Xlo) {
  const int row = blockIdx.x * 4 + (threadIdx.x >> 6);
  const int lane = threadIdx.x & 63;
  float4 v[4];
  float ss = 0.f;
#pragma unroll
  for (int i = 0; i < 4; ++i) {
    v[i] = *reinterpret_cast<const float4*>(
        &x[(size_t)row * DIM + lane * 4 + i * 256]);
    ss += v[i].x * v[i].x + v[i].y * v[i].y + v[i].z * v[i].z + v[i].w * v[i].w;
  }
  const float rstd = rsqrtf(wave_reduce_sum(ss) * (1.0f / DIM) + EPSV);
#pragma unroll
  for (int i = 0; i < 4; ++i) {
    const int d4 = lane * 4 + i * 256;
    const float4 w = *reinterpret_cast<const float4*>(&norm_w[d4]);
    const float hv[4] = {v[i].x * rstd * w.x, v[i].y * rstd * w.y,
                         v[i].z * rstd * w.z, v[i].w * rstd * w.w};
    ushort4 hh, ll;
    hh.x = f2bf_rne(hv[0]); ll.x = f2bf_rne(hv[0] - bf2f(hh.x));
    hh.y = f2bf_rne(hv[1]); ll.y = f2bf_rne(hv[1] - bf2f(hh.y));
    hh.z = f2bf_rne(hv[2]); ll.z = f2bf_rne(hv[2] - bf2f(hh.z));
    hh.w = f2bf_rne(hv[3]); ll.w = f2bf_rne(hv[3] - bf2f(hh.w));
    *reinterpret_cast<ushort4*>(&Xhi[(size_t)row * DIM + d4]) = hh;
    *reinterpret_cast<ushort4*>(&Xlo[(size_t)row * DIM + d4]) = ll;
  }
}

// ---------------------------------------------------------------------------
// splitw: W[K][N] fp32 -> transposed bf16 hi/lo Wt[N][K]. 32x32 LDS tiles.
// ---------------------------------------------------------------------------
__global__ __launch_bounds__(256) void splitw_kernel(
    const float* __restrict__ W, unsigned short* __restrict__ Whi,
    unsigned short* __restrict__ Wlo, int K, int N) {
  __shared__ float t[32][33];
  const int n0 = blockIdx.x * 32, k0 = blockIdx.y * 32;
  const int c = threadIdx.x & 31, r = threadIdx.x >> 5;  // r: 0..7
#pragma unroll
  for (int i = 0; i < 4; ++i)
    t[r + i * 8][c] = W[(size_t)(k0 + r + i * 8) * N + n0 + c];
  __syncthreads();
#pragma unroll
  for (int i = 0; i < 4; ++i) {
    const int n = n0 + r + i * 8, k = k0 + c;
    const float v = t[c][r + i * 8];
    const unsigned short h = f2bf_rne(v);
    Whi[(size_t)n * K + k] = h;
    Wlo[(size_t)n * K + k] = f2bf_rne(v - bf2f(h));
  }
}

// ---------------------------------------------------------------------------
// Split MFMA GEMM, templated on stream count.
//   NT=4: bf16x3 (Ahi,Alo,Bhi,Blo staged; hi*hi + hi*lo + lo*hi)
//   NT=2: plain bf16 (Ahi,Bhi staged; 1 MFMA)
// C[M][N] = A[M][1024] * B^T[N][1024] (both k-contiguous; A row stride lda).
// 128x128 tile, BK=32, 4 waves (2x2 quadrants), acc 4x4 f32x4 per wave.
// LDS NT*8KB; global_load_lds width-16 linear dest; XOR swizzle
// b ^= ((b>>7)&7)<<4 on SOURCE logical byte and frag READ byte (involution,
// both sides) -> measured SQ_LDS_BANK_CONFLICT = 0.
//  RESID: C = resid*res_scale[0] + A*B (fp32 out). OBF16: C written as bf16.
// ---------------------------------------------------------------------------
template <int NT, bool RESID, bool OBF16>
__global__ __launch_bounds__(256) void gemm_kernel(
    const unsigned short* __restrict__ Ahi, const unsigned short* __restrict__ Alo,
    const unsigned short* __restrict__ Bhi, const unsigned short* __restrict__ Blo,
    float* __restrict__ Cf, unsigned short* __restrict__ Ch, int N, int lda,
    const float* __restrict__ resid, const float* __restrict__ res_scale) {
  __shared__ __align__(16) unsigned short lds[NT * 4096];

  const int tid = threadIdx.x;
  const int lane = tid & 63;
  const int wr = tid >> 7;         // wave quadrant row (0..1)
  const int wc = (tid >> 6) & 1;   // wave quadrant col (0..1)

  // XCD-aware block swizzle (nwg divisible by 8 for all GEMMs here)
  const int nwg = gridDim.x * gridDim.y;
  int id = blockIdx.y * gridDim.x + blockIdx.x;
  id = (id & 7) * (nwg >> 3) + (id >> 3);
  const int bx = id % gridDim.x;
  const int by = id / gridDim.x;
  const int bm = by * 128;
  const int bn = bx * 128;

  // Staging: 2*NT x 16B per thread per K-step. Linear LDS byte o; tensor
  // t = o>>13; within-tile ot = o&8191; source logical byte b = ot^swz(ot).
  const unsigned short* pg[2 * NT];
  unsigned int lofs[2 * NT];
#pragma unroll
  for (int i = 0; i < 2 * NT; ++i) {
    const int o = tid * 16 + i * 4096;
    const int t = o >> 13;
    const int ot = o & 8191;
    const int b = ot ^ (((ot >> 7) & 7) << 4);
    const int r = b >> 6;             // tile row 0..127
    const int ck = (b & 63) >> 1;     // k offset (ushorts): 0,8,16,24
    const unsigned short* base;
    bool aside;
    if constexpr (NT == 4) {
      base = (t == 0) ? Ahi : (t == 1) ? Alo : (t == 2) ? Bhi : Blo;
      aside = (t < 2);
    } else {
      base = (t == 0) ? Ahi : Bhi;
      aside = (t < 1);
    }
    const int stride = aside ? lda : 1024;
    const int rowg = (aside ? bm : bn) + r;
    pg[i] = base + (size_t)rowg * stride + ck;
    lofs[i] = (unsigned int)(o >> 1);
  }

  // Fragment read offsets (ushort idx), swizzled. B tiles start at NT/2*4096.
  unsigned int aoff[4], boff[4];
#pragma unroll
  for (int i = 0; i < 4; ++i) {
    int ba = (wr * 64 + i * 16 + (lane & 15)) * 64 + (lane >> 4) * 16;
    ba ^= ((ba >> 7) & 7) << 4;
    aoff[i] = (unsigned int)(ba >> 1);
    int bb = (wc * 64 + i * 16 + (lane & 15)) * 64 + (lane >> 4) * 16;
    bb ^= ((bb >> 7) & 7) << 4;
    boff[i] = (unsigned int)(bb >> 1) + (NT / 2) * 4096;
  }

  f32x4 acc[4][4];
#pragma unroll
  for (int mi = 0; mi < 4; ++mi)
#pragma unroll
    for (int ni = 0; ni < 4; ++ni) {
      acc[mi][ni][0] = 0.f; acc[mi][ni][1] = 0.f;
      acc[mi][ni][2] = 0.f; acc[mi][ni][3] = 0.f;
    }

  for (int k0 = 0; k0 < 1024; k0 += 32) {
#pragma unroll
    for (int i = 0; i < 2 * NT; ++i)
      __builtin_amdgcn_global_load_lds(
          (const __attribute__((address_space(1))) void*)(pg[i] + k0),
          (__attribute__((address_space(3))) void*)(&lds[lofs[i]]), 16, 0, 0);
    __syncthreads();  // compiler drains vmcnt before s_barrier

    short8v bh[4], bl[4];
#pragma unroll
    for (int ni = 0; ni < 4; ++ni) {
      bh[ni] = *reinterpret_cast<const short8v*>(&lds[boff[ni]]);
      if constexpr (NT == 4)
        bl[ni] = *reinterpret_cast<const short8v*>(&lds[boff[ni] + 4096]);
    }
#pragma unroll
    for (int mi = 0; mi < 4; ++mi) {
      const short8v ah = *reinterpret_cast<const short8v*>(&lds[aoff[mi]]);
#pragma unroll
      for (int ni = 0; ni < 4; ++ni)
        acc[mi][ni] = __builtin_amdgcn_mfma_f32_16x16x32_bf16(ah, bh[ni], acc[mi][ni], 0, 0, 0);
      if constexpr (NT == 4) {
        const short8v al = *reinterpret_cast<const short8v*>(&lds[aoff[mi] + 4096]);
#pragma unroll
        for (int ni = 0; ni < 4; ++ni) {
          acc[mi][ni] = __builtin_amdgcn_mfma_f32_16x16x32_bf16(ah, bl[ni], acc[mi][ni], 0, 0, 0);
          acc[mi][ni] = __builtin_amdgcn_mfma_f32_16x16x32_bf16(al, bh[ni], acc[mi][ni], 0, 0, 0);
        }
      }
    }
    __syncthreads();
  }

  // Epilogue: C/D layout col=lane&15, row=(lane>>4)*4+reg (verified).
  const float rscale = RESID ? res_scale[0] : 0.0f;
#pragma unroll
  for (int mi = 0; mi < 4; ++mi) {
    const int row0 = bm + wr * 64 + mi * 16 + (lane >> 4) * 4;
#pragma unroll
    for (int ni = 0; ni < 4; ++ni) {
      const int col = bn + wc * 64 + ni * 16 + (lane & 15);
#pragma unroll
      for (int r = 0; r < 4; ++r) {
        const size_t idx = (size_t)(row0 + r) * N + col;
        float v = acc[mi][ni][r];
        if constexpr (RESID) v = fmaf(resid[idx], rscale, v);
        if constexpr (OBF16) Ch[idx] = f2bf_rne(v);
        else                 Cf[idx] = v;
      }
    }
  }
}

// ---------------------------------------------------------------------------
// Phase A: depthwise causal conv(K=4) + bias + silu, then LOCAL scan within
// each chunk of 32 steps. Grid: (DIM/256, NCHUNK, BATCH). xb stride = DIM.
// ---------------------------------------------------------------------------
__global__ __launch_bounds__(256) void phaseA_kernel(
    const float* __restrict__ xb, const float* __restrict__ conv_w,
    const float* __restrict__ conv_b, const float* __restrict__ decay,
    float* __restrict__ hs, float* __restrict__ fbuf) {
  const int d = blockIdx.x * 256 + threadIdx.x;
  const int c = blockIdx.y;
  const int b = blockIdx.z;
  const int t0 = c * CHUNK;

  const float w0 = conv_w[d * KCONV + 0];
  const float w1 = conv_w[d * KCONV + 1];
  const float w2 = conv_w[d * KCONV + 2];
  const float w3 = conv_w[d * KCONV + 3];
  const float cb = conv_b[d];
  const float a = 1.0f / (1.0f + expf(-decay[d]));

  const size_t rowbase = ((size_t)b * SEQ + t0) * DIM + d;
  float xm1 = 0.f, xm2 = 0.f, xm3 = 0.f;
  if (t0 >= 1) xm1 = xb[rowbase - 1 * (size_t)DIM];
  if (t0 >= 2) xm2 = xb[rowbase - 2 * (size_t)DIM];
  if (t0 >= 3) xm3 = xb[rowbase - 3 * (size_t)DIM];

  float h = 0.f;
  size_t src = rowbase;
#pragma unroll 4
  for (int t = 0; t < CHUNK; ++t) {
    const float cur = xb[src];
    const float conv =
        fmaf(w0, xm3, fmaf(w1, xm2, fmaf(w2, xm1, fmaf(w3, cur, cb))));
    const float u = conv / (1.0f + expf(-conv));  // silu
    h = fmaf(a, h, u);
    hs[src] = h;                      // hs has same layout as xb
    xm3 = xm2; xm2 = xm1; xm1 = cur;
    src += DIM;
  }
  fbuf[((size_t)b * NCHUNK + c) * DIM + d] = h;
}

// ---------------------------------------------------------------------------
// Phase B: sequential carry propagation across chunks. Grid: (DIM/256, BATCH).
// ---------------------------------------------------------------------------
__global__ __launch_bounds__(256) void phaseB_kernel(
    const float* __restrict__ decay, const float* __restrict__ fbuf,
    float* __restrict__ cbuf) {
  const int d = blockIdx.x * 256 + threadIdx.x;
  const int b = blockIdx.y;
  const float a = 1.0f / (1.0f + expf(-decay[d]));
  const float aL = exp2f((float)CHUNK * __log2f(a));
  float carry = 0.f;
  for (int c = 0; c < NCHUNK; ++c) {
    const size_t idx = ((size_t)b * NCHUNK + c) * DIM + d;
    cbuf[idx] = carry;
    carry = fmaf(aL, carry, fbuf[idx]);
  }
}

// ---------------------------------------------------------------------------
// Phase C: h_full = hs_local + a^(j+1)*carry; y = rmsnorm(h_full, gate_w) *
// silu(z), emitted as bf16 (hi only — feeds plain-bf16 GEMM2).
// One WAVE per row; 4 rows per block.
// ---------------------------------------------------------------------------
__global__ __launch_bounds__(256) void phaseC_kernel(
    const unsigned short* __restrict__ z, const float* __restrict__ hs,
    const float* __restrict__ cbuf, const float* __restrict__ decay,
    const float* __restrict__ gate_w, unsigned short* __restrict__ Yhi) {
  const int row = blockIdx.x * 4 + (threadIdx.x >> 6);
  const int lane = threadIdx.x & 63;
  const int b = row >> 12;             // SEQ = 4096
  const int t = row & (SEQ - 1);
  const int c = t / CHUNK;
  const float e = (float)((t & (CHUNK - 1)) + 1);

  float hv[16];
  float ss = 0.f;
#pragma unroll
  for (int i = 0; i < 4; ++i) {
    const int d4 = lane * 4 + i * 256;
    const float4 dc = *reinterpret_cast<const float4*>(&decay[d4]);
    const float4 cv = *reinterpret_cast<const float4*>(
        &cbuf[((size_t)b * NCHUNK + c) * DIM + d4]);
    const float4 hl = *reinterpret_cast<const float4*>(
        &hs[(size_t)row * DIM + d4]);
    const float ad[4] = {dc.x, dc.y, dc.z, dc.w};
    const float cr[4] = {cv.x, cv.y, cv.z, cv.w};
    const float hh[4] = {hl.x, hl.y, hl.z, hl.w};
#pragma unroll
    for (int j = 0; j < 4; ++j) {
      const float a = 1.0f / (1.0f + expf(-ad[j]));
      const float ae = exp2f(e * __log2f(a));
      const float v = fmaf(ae, cr[j], hh[j]);
      hv[i * 4 + j] = v;
      ss = fmaf(v, v, ss);
    }
  }
  const float rstd = rsqrtf(wave_reduce_sum(ss) * (1.0f / DIM) + EPSV);
#pragma unroll
  for (int i = 0; i < 4; ++i) {
    const int d4 = lane * 4 + i * 256;
    const ushort4 zs = *reinterpret_cast<const ushort4*>(
        &z[(size_t)row * DIM + d4]);
    const float4 gw = *reinterpret_cast<const float4*>(&gate_w[d4]);
    const float zf[4] = {bf2f(zs.x), bf2f(zs.y), bf2f(zs.z), bf2f(zs.w)};
    const float gf[4] = {gw.x, gw.y, gw.z, gw.w};
    ushort4 yo;
    unsigned short* yp = &yo.x;
#pragma unroll
    for (int j = 0; j < 4; ++j) {
      const float sz = zf[j] / (1.0f + expf(-zf[j]));  // silu(z)
      yp[j] = f2bf_rne(hv[i * 4 + j] * rstd * gf[j] * sz);
    }
    *reinterpret_cast<ushort4*>(&Yhi[(size_t)row * DIM + d4]) = yo;
  }
}

// ---------------------------------------------------------------------------
extern "C" void kernel_launch(void* const* d_in, const int* in_sizes, int n_in,
                              void* d_out, int out_size, void* d_ws,
                              size_t ws_size, hipStream_t stream) {
  const float* x = (const float*)d_in[0];
  const float* norm_w = (const float*)d_in[1];
  const float* in_w = (const float*)d_in[2];
  const float* conv_w = (const float*)d_in[3];
  const float* conv_b = (const float*)d_in[4];
  const float* decay = (const float*)d_in[5];
  const float* gate_w = (const float*)d_in[6];
  const float* out_w = (const float*)d_in[7];
  const float* res_scale = (const float*)d_in[8];
  float* out = (float*)d_out;

  // Workspace layout (bytes), peak 213,909,504 (~204 MiB):
  //  [0,       67.1M)  xb fp32 [M][1024]   (GEMM1a out; phaseA in)
  //  [67.1M,  100.7M)  z  bf16 [M][1024]   (GEMM1z out; phaseC in)
  //  [100.7M, 134.2M)  yhi bf16 [M][1024]  (phaseC out; GEMM2 A)
  //  [134.2M, 201.3M)  xhi|xlo bf16        (GEMM1 A); after GEMM1z dead ->
  //                    hs fp32 [M][1024] overlays it (phaseA out, phaseC in)
  //  [201.3M, 213.9M)  w1hi|w1lo|w2hi|w2lo (bf16, transposed)
  //  fbuf/cbuf (2 MB each) live in d_out scratch (dead until GEMM2 rewrite).
  const size_t NEEDED = 213909504;
  if (ws_size < NEEDED) return;  // clean diagnostic fail instead of OOB fault

  char* w8 = (char*)d_ws;
  float* xb = (float*)(w8);
  unsigned short* zbf = (unsigned short*)(w8 + 67108864);
  unsigned short* yhi = (unsigned short*)(w8 + 100663296);
  unsigned short* xhi = (unsigned short*)(w8 + 134217728);
  unsigned short* xlo = (unsigned short*)(w8 + 167772160);
  float* hs = (float*)(w8 + 134217728);            // overlays xhi/xlo
  unsigned short* w1hi = (unsigned short*)(w8 + 201326592);
  unsigned short* w1lo = (unsigned short*)(w8 + 205520896);
  unsigned short* w2hi = (unsigned short*)(w8 + 209715200);
  unsigned short* w2lo = (unsigned short*)(w8 + 211812352);
  float* fbuf = (float*)d_out;                     // scratch until GEMM2
  float* cbuf = fbuf + (size_t)BATCH * NCHUNK * DIM;

  // 1. fused RMSNorm + bf16 split of x (wave per row)
  splitx_kernel<<<MROWS / 4, 256, 0, stream>>>(x, norm_w, xhi, xlo);

  // 2. weight transpose+split (Wt[N][K] bf16 hi/lo)
  splitw_kernel<<<dim3((2 * DIM) / 32, DIM / 32), 256, 0, stream>>>(
      in_w, w1hi, w1lo, DIM, 2 * DIM);
  splitw_kernel<<<dim3(DIM / 32, DIM / 32), 256, 0, stream>>>(
      out_w, w2hi, w2lo, DIM, DIM);

  // 3. GEMM1a (bf16x3): xb = norm(x) @ in_w[:, :1024]   fp32 out
  gemm_kernel<4, false, false><<<dim3(8, 128), 256, 0, stream>>>(
      xhi, xlo, w1hi, w1lo, xb, nullptr, DIM, 1024, nullptr, nullptr);

  // 4. GEMM1z (bf16x1): z = norm(x) @ in_w[:, 1024:]    bf16 out
  gemm_kernel<2, false, true><<<dim3(8, 128), 256, 0, stream>>>(
      xhi, nullptr, w1hi + (size_t)1024 * 1024, nullptr, nullptr, zbf,
      DIM, 1024, nullptr, nullptr);

  // 5. conv + silu + local scan (writes hs over dead xhi/xlo)
  phaseA_kernel<<<dim3(DIM / 256, NCHUNK, BATCH), 256, 0, stream>>>(
      xb, conv_w, conv_b, decay, hs, fbuf);

  // 6. chunk carry propagation
  phaseB_kernel<<<dim3(DIM / 256, BATCH), 256, 0, stream>>>(decay, fbuf, cbuf);

  // 7. carry injection + gated rmsnorm * silu(z) -> yhi (bf16)
  phaseC_kernel<<<MROWS / 4, 256, 0, stream>>>(zbf, hs, cbuf, decay, gate_w, yhi);

  // 8. GEMM2 (bf16x1): out = x * res_scale + y @ out_w
  gemm_kernel<2, true, false><<<dim3(8, 128), 256, 0, stream>>>(
      yhi, nullptr, w2hi, nullptr, out, nullptr, DIM, 1024, x, res_scale);
}

// Round 5
// 411.342 us; speedup vs baseline: 1.2227x; 1.0242x over previous
//
#include <hip/hip_runtime.h>
#include <cstddef>

// Problem constants (match reference)
#define BATCH 4
#define SEQ   4096
#define DIM   1024
#define KCONV 4
#define EPSV  1e-6f
#define MROWS (BATCH * SEQ)      // 16384
#define CHUNK 32
#define NCHUNK (SEQ / CHUNK)     // 128

using short8v = __attribute__((ext_vector_type(8))) short;  // 8 bf16 (4 VGPRs)
using f32x4   = __attribute__((ext_vector_type(4))) float;  // MFMA acc

// bf16 helpers (RNE)
__device__ __forceinline__ unsigned short f2bf_rne(float f) {
  unsigned int u = __float_as_uint(f);
  u += 0x7FFFu + ((u >> 16) & 1u);
  return (unsigned short)(u >> 16);
}
__device__ __forceinline__ float bf2f(unsigned short h) {
  return __uint_as_float((unsigned int)h << 16);
}

// Full-wave (64-lane) sum reduction; all lanes get the total.
__device__ __forceinline__ float wave_reduce_sum(float v) {
#pragma unroll
  for (int off = 32; off > 0; off >>= 1)
    v += __shfl_xor(v, off, 64);
  return v;
}

// ---------------------------------------------------------------------------
// splitx: fused input RMSNorm + bf16 hi/lo split. One WAVE per row (no
// barriers); block = 4 waves = 4 rows. Each lane handles 16 elements.
// ---------------------------------------------------------------------------
__global__ __launch_bounds__(256) void splitx_kernel(
    const float* __restrict__ x, const float* __restrict__ norm_w,
    unsigned short* __restrict__ Xhi, unsigned short* __restrict__ Xlo) {
  const int row = blockIdx.x * 4 + (threadIdx.x >> 6);
  const int lane = threadIdx.x & 63;
  float4 v[4];
  float ss = 0.f;
#pragma unroll
  for (int i = 0; i < 4; ++i) {
    v[i] = *reinterpret_cast<const float4*>(
        &x[(size_t)row * DIM + lane * 4 + i * 256]);
    ss += v[i].x * v[i].x + v[i].y * v[i].y + v[i].z * v[i].z + v[i].w * v[i].w;
  }
  const float rstd = rsqrtf(wave_reduce_sum(ss) * (1.0f / DIM) + EPSV);
#pragma unroll
  for (int i = 0; i < 4; ++i) {
    const int d4 = lane * 4 + i * 256;
    const float4 w = *reinterpret_cast<const float4*>(&norm_w[d4]);
    const float hv[4] = {v[i].x * rstd * w.x, v[i].y * rstd * w.y,
                         v[i].z * rstd * w.z, v[i].w * rstd * w.w};
    ushort4 hh, ll;
    hh.x = f2bf_rne(hv[0]); ll.x = f2bf_rne(hv[0] - bf2f(hh.x));
    hh.y = f2bf_rne(hv[1]); ll.y = f2bf_rne(hv[1] - bf2f(hh.y));
    hh.z = f2bf_rne(hv[2]); ll.z = f2bf_rne(hv[2] - bf2f(hh.z));
    hh.w = f2bf_rne(hv[3]); ll.w = f2bf_rne(hv[3] - bf2f(hh.w));
    *reinterpret_cast<ushort4*>(&Xhi[(size_t)row * DIM + d4]) = hh;
    *reinterpret_cast<ushort4*>(&Xlo[(size_t)row * DIM + d4]) = ll;
  }
}

// ---------------------------------------------------------------------------
// splitw2: both weights in one launch. blockIdx.z: 0 -> in_w [1024][2048],
// 1 -> out_w [1024][1024] (x-blocks >= 32 exit, block-uniform).
// W[K][N] fp32 -> transposed bf16 hi/lo Wt[N][K] via 32x32 LDS tiles.
// ---------------------------------------------------------------------------
__global__ __launch_bounds__(256) void splitw2_kernel(
    const float* __restrict__ W0, unsigned short* __restrict__ W0hi,
    unsigned short* __restrict__ W0lo, const float* __restrict__ W1,
    unsigned short* __restrict__ W1hi, unsigned short* __restrict__ W1lo) {
  const float* W; unsigned short *Whi, *Wlo; int N;
  if (blockIdx.z == 0) { W = W0; Whi = W0hi; Wlo = W0lo; N = 2048; }
  else {
    if (blockIdx.x >= 32) return;   // uniform: whole block exits together
    W = W1; Whi = W1hi; Wlo = W1lo; N = 1024;
  }
  const int K = 1024;
  __shared__ float t[32][33];
  const int n0 = blockIdx.x * 32, k0 = blockIdx.y * 32;
  const int c = threadIdx.x & 31, r = threadIdx.x >> 5;  // r: 0..7
#pragma unroll
  for (int i = 0; i < 4; ++i)
    t[r + i * 8][c] = W[(size_t)(k0 + r + i * 8) * N + n0 + c];
  __syncthreads();
#pragma unroll
  for (int i = 0; i < 4; ++i) {
    const int n = n0 + r + i * 8, k = k0 + c;
    const float v = t[c][r + i * 8];
    const unsigned short h = f2bf_rne(v);
    Whi[(size_t)n * K + k] = h;
    Wlo[(size_t)n * K + k] = f2bf_rne(v - bf2f(h));
  }
}

// ---------------------------------------------------------------------------
// Split MFMA GEMM, templated on stream count.
//   NT=4: bf16x3 (Ahi,Alo,Bhi,Blo staged; hi*hi + hi*lo + lo*hi)
//   NT=2: plain bf16 (Ahi,Bhi staged; 1 MFMA)
// C[M][N] = A[M][1024] * B^T[N][1024] (both k-contiguous; A row stride lda).
// 128x128 tile, BK=32, 4 waves (2x2 quadrants), acc 4x4 f32x4 per wave.
// LDS NT*8KB; global_load_lds width-16 linear dest; XOR swizzle
// b ^= ((b>>7)&7)<<4 on SOURCE logical byte and frag READ byte (involution,
// both sides) -> measured SQ_LDS_BANK_CONFLICT = 0.
// NEW: block-phase stagger via s_sleep keyed on (swizzled id & 3) to
// de-phase-lock co-resident blocks' drain/MFMA bursts (experiment; see
// round-5 theory — offsets persist because blocks never inter-sync).
//  RESID: C = resid*res_scale[0] + A*B (fp32 out). OBF16: C written as bf16.
// ---------------------------------------------------------------------------
template <int NT, bool RESID, bool OBF16>
__global__ __launch_bounds__(256) void gemm_kernel(
    const unsigned short* __restrict__ Ahi, const unsigned short* __restrict__ Alo,
    const unsigned short* __restrict__ Bhi, const unsigned short* __restrict__ Blo,
    float* __restrict__ Cf, unsigned short* __restrict__ Ch, int N, int lda,
    const float* __restrict__ resid, const float* __restrict__ res_scale) {
  __shared__ __align__(16) unsigned short lds[NT * 4096];

  const int tid = threadIdx.x;
  const int lane = tid & 63;
  const int wr = tid >> 7;         // wave quadrant row (0..1)
  const int wc = (tid >> 6) & 1;   // wave quadrant col (0..1)

  // XCD-aware block swizzle (nwg divisible by 8 for all GEMMs here)
  const int nwg = gridDim.x * gridDim.y;
  int id = blockIdx.y * gridDim.x + blockIdx.x;
  id = (id & 7) * (nwg >> 3) + (id >> 3);
  const int bx = id % gridDim.x;
  const int by = id / gridDim.x;
  const int bm = by * 128;
  const int bn = bx * 128;

  // De-phase co-resident blocks (s_sleep imm units = 64 cy): 0/512/1024/1536.
  switch (id & 3) {
    case 1: __builtin_amdgcn_s_sleep(8);  break;
    case 2: __builtin_amdgcn_s_sleep(16); break;
    case 3: __builtin_amdgcn_s_sleep(24); break;
    default: break;
  }

  // Staging: 2*NT x 16B per thread per K-step. Linear LDS byte o; tensor
  // t = o>>13; within-tile ot = o&8191; source logical byte b = ot^swz(ot).
  const unsigned short* pg[2 * NT];
  unsigned int lofs[2 * NT];
#pragma unroll
  for (int i = 0; i < 2 * NT; ++i) {
    const int o = tid * 16 + i * 4096;
    const int t = o >> 13;
    const int ot = o & 8191;
    const int b = ot ^ (((ot >> 7) & 7) << 4);
    const int r = b >> 6;             // tile row 0..127
    const int ck = (b & 63) >> 1;     // k offset (ushorts): 0,8,16,24
    const unsigned short* base;
    bool aside;
    if constexpr (NT == 4) {
      base = (t == 0) ? Ahi : (t == 1) ? Alo : (t == 2) ? Bhi : Blo;
      aside = (t < 2);
    } else {
      base = (t == 0) ? Ahi : Bhi;
      aside = (t < 1);
    }
    const int stride = aside ? lda : 1024;
    const int rowg = (aside ? bm : bn) + r;
    pg[i] = base + (size_t)rowg * stride + ck;
    lofs[i] = (unsigned int)(o >> 1);
  }

  // Fragment read offsets (ushort idx), swizzled. B tiles start at NT/2*4096.
  unsigned int aoff[4], boff[4];
#pragma unroll
  for (int i = 0; i < 4; ++i) {
    int ba = (wr * 64 + i * 16 + (lane & 15)) * 64 + (lane >> 4) * 16;
    ba ^= ((ba >> 7) & 7) << 4;
    aoff[i] = (unsigned int)(ba >> 1);
    int bb = (wc * 64 + i * 16 + (lane & 15)) * 64 + (lane >> 4) * 16;
    bb ^= ((bb >> 7) & 7) << 4;
    boff[i] = (unsigned int)(bb >> 1) + (NT / 2) * 4096;
  }

  f32x4 acc[4][4];
#pragma unroll
  for (int mi = 0; mi < 4; ++mi)
#pragma unroll
    for (int ni = 0; ni < 4; ++ni) {
      acc[mi][ni][0] = 0.f; acc[mi][ni][1] = 0.f;
      acc[mi][ni][2] = 0.f; acc[mi][ni][3] = 0.f;
    }

  for (int k0 = 0; k0 < 1024; k0 += 32) {
#pragma unroll
    for (int i = 0; i < 2 * NT; ++i)
      __builtin_amdgcn_global_load_lds(
          (const __attribute__((address_space(1))) void*)(pg[i] + k0),
          (__attribute__((address_space(3))) void*)(&lds[lofs[i]]), 16, 0, 0);
    __syncthreads();  // compiler drains vmcnt before s_barrier

    short8v bh[4], bl[4];
#pragma unroll
    for (int ni = 0; ni < 4; ++ni) {
      bh[ni] = *reinterpret_cast<const short8v*>(&lds[boff[ni]]);
      if constexpr (NT == 4)
        bl[ni] = *reinterpret_cast<const short8v*>(&lds[boff[ni] + 4096]);
    }
#pragma unroll
    for (int mi = 0; mi < 4; ++mi) {
      const short8v ah = *reinterpret_cast<const short8v*>(&lds[aoff[mi]]);
#pragma unroll
      for (int ni = 0; ni < 4; ++ni)
        acc[mi][ni] = __builtin_amdgcn_mfma_f32_16x16x32_bf16(ah, bh[ni], acc[mi][ni], 0, 0, 0);
      if constexpr (NT == 4) {
        const short8v al = *reinterpret_cast<const short8v*>(&lds[aoff[mi] + 4096]);
#pragma unroll
        for (int ni = 0; ni < 4; ++ni) {
          acc[mi][ni] = __builtin_amdgcn_mfma_f32_16x16x32_bf16(ah, bl[ni], acc[mi][ni], 0, 0, 0);
          acc[mi][ni] = __builtin_amdgcn_mfma_f32_16x16x32_bf16(al, bh[ni], acc[mi][ni], 0, 0, 0);
        }
      }
    }
    __syncthreads();
  }

  // Epilogue: C/D layout col=lane&15, row=(lane>>4)*4+reg (verified).
  const float rscale = RESID ? res_scale[0] : 0.0f;
#pragma unroll
  for (int mi = 0; mi < 4; ++mi) {
    const int row0 = bm + wr * 64 + mi * 16 + (lane >> 4) * 4;
#pragma unroll
    for (int ni = 0; ni < 4; ++ni) {
      const int col = bn + wc * 64 + ni * 16 + (lane & 15);
#pragma unroll
      for (int r = 0; r < 4; ++r) {
        const size_t idx = (size_t)(row0 + r) * N + col;
        float v = acc[mi][ni][r];
        if constexpr (RESID) v = fmaf(resid[idx], rscale, v);
        if constexpr (OBF16) Ch[idx] = f2bf_rne(v);
        else                 Cf[idx] = v;
      }
    }
  }
}

// ---------------------------------------------------------------------------
// Phase A: depthwise causal conv(K=4) + bias + silu, then LOCAL scan within
// each chunk of 32 steps. Grid: (DIM/256, NCHUNK, BATCH). xb stride = DIM.
// ---------------------------------------------------------------------------
__global__ __launch_bounds__(256) void phaseA_kernel(
    const float* __restrict__ xb, const float* __restrict__ conv_w,
    const float* __restrict__ conv_b, const float* __restrict__ decay,
    float* __restrict__ hs, float* __restrict__ fbuf) {
  const int d = blockIdx.x * 256 + threadIdx.x;
  const int c = blockIdx.y;
  const int b = blockIdx.z;
  const int t0 = c * CHUNK;

  const float w0 = conv_w[d * KCONV + 0];
  const float w1 = conv_w[d * KCONV + 1];
  const float w2 = conv_w[d * KCONV + 2];
  const float w3 = conv_w[d * KCONV + 3];
  const float cb = conv_b[d];
  const float a = 1.0f / (1.0f + expf(-decay[d]));

  const size_t rowbase = ((size_t)b * SEQ + t0) * DIM + d;
  float xm1 = 0.f, xm2 = 0.f, xm3 = 0.f;
  if (t0 >= 1) xm1 = xb[rowbase - 1 * (size_t)DIM];
  if (t0 >= 2) xm2 = xb[rowbase - 2 * (size_t)DIM];
  if (t0 >= 3) xm3 = xb[rowbase - 3 * (size_t)DIM];

  float h = 0.f;
  size_t src = rowbase;
#pragma unroll 4
  for (int t = 0; t < CHUNK; ++t) {
    const float cur = xb[src];
    const float conv =
        fmaf(w0, xm3, fmaf(w1, xm2, fmaf(w2, xm1, fmaf(w3, cur, cb))));
    const float u = conv / (1.0f + expf(-conv));  // silu
    h = fmaf(a, h, u);
    hs[src] = h;                      // hs has same layout as xb
    xm3 = xm2; xm2 = xm1; xm1 = cur;
    src += DIM;
  }
  fbuf[((size_t)b * NCHUNK + c) * DIM + d] = h;
}

// ---------------------------------------------------------------------------
// Phase B: sequential carry propagation across chunks. Grid: (DIM/256, BATCH).
// Group-of-8 register prefetch (static indices): 8 loads in flight, one
// load-latency per 8 iterations instead of per iteration.
// ---------------------------------------------------------------------------
__global__ __launch_bounds__(256) void phaseB_kernel(
    const float* __restrict__ decay, const float* __restrict__ fbuf,
    float* __restrict__ cbuf) {
  const int d = blockIdx.x * 256 + threadIdx.x;
  const int b = blockIdx.y;
  const float a = 1.0f / (1.0f + expf(-decay[d]));
  const float aL = exp2f((float)CHUNK * __log2f(a));
  const float* fp = fbuf + (size_t)b * NCHUNK * DIM + d;
  float* cp = cbuf + (size_t)b * NCHUNK * DIM + d;
  float carry = 0.f;
  for (int c0 = 0; c0 < NCHUNK; c0 += 8) {
    float v[8];
#pragma unroll
    for (int i = 0; i < 8; ++i) v[i] = fp[(size_t)(c0 + i) * DIM];
#pragma unroll
    for (int i = 0; i < 8; ++i) {
      cp[(size_t)(c0 + i) * DIM] = carry;
      carry = fmaf(aL, carry, v[i]);
    }
  }
}

// ---------------------------------------------------------------------------
// Phase C: h_full = hs_local + a^(j+1)*carry; y = rmsnorm(h_full, gate_w) *
// silu(z), emitted as bf16 (hi only — feeds plain-bf16 GEMM2).
// One WAVE per row; 4 rows per block.
// ---------------------------------------------------------------------------
__global__ __launch_bounds__(256) void phaseC_kernel(
    const unsigned short* __restrict__ z, const float* __restrict__ hs,
    const float* __restrict__ cbuf, const float* __restrict__ decay,
    const float* __restrict__ gate_w, unsigned short* __restrict__ Yhi) {
  const int row = blockIdx.x * 4 + (threadIdx.x >> 6);
  const int lane = threadIdx.x & 63;
  const int b = row >> 12;             // SEQ = 4096
  const int t = row & (SEQ - 1);
  const int c = t / CHUNK;
  const float e = (float)((t & (CHUNK - 1)) + 1);

  float hv[16];
  float ss = 0.f;
#pragma unroll
  for (int i = 0; i < 4; ++i) {
    const int d4 = lane * 4 + i * 256;
    const float4 dc = *reinterpret_cast<const float4*>(&decay[d4]);
    const float4 cv = *reinterpret_cast<const float4*>(
        &cbuf[((size_t)b * NCHUNK + c) * DIM + d4]);
    const float4 hl = *reinterpret_cast<const float4*>(
        &hs[(size_t)row * DIM + d4]);
    const float ad[4] = {dc.x, dc.y, dc.z, dc.w};
    const float cr[4] = {cv.x, cv.y, cv.z, cv.w};
    const float hh[4] = {hl.x, hl.y, hl.z, hl.w};
#pragma unroll
    for (int j = 0; j < 4; ++j) {
      const float a = 1.0f / (1.0f + expf(-ad[j]));
      const float ae = exp2f(e * __log2f(a));
      const float v = fmaf(ae, cr[j], hh[j]);
      hv[i * 4 + j] = v;
      ss = fmaf(v, v, ss);
    }
  }
  const float rstd = rsqrtf(wave_reduce_sum(ss) * (1.0f / DIM) + EPSV);
#pragma unroll
  for (int i = 0; i < 4; ++i) {
    const int d4 = lane * 4 + i * 256;
    const ushort4 zs = *reinterpret_cast<const ushort4*>(
        &z[(size_t)row * DIM + d4]);
    const float4 gw = *reinterpret_cast<const float4*>(&gate_w[d4]);
    const float zf[4] = {bf2f(zs.x), bf2f(zs.y), bf2f(zs.z), bf2f(zs.w)};
    const float gf[4] = {gw.x, gw.y, gw.z, gw.w};
    ushort4 yo;
    unsigned short* yp = &yo.x;
#pragma unroll
    for (int j = 0; j < 4; ++j) {
      const float sz = zf[j] / (1.0f + expf(-zf[j]));  // silu(z)
      yp[j] = f2bf_rne(hv[i * 4 + j] * rstd * gf[j] * sz);
    }
    *reinterpret_cast<ushort4*>(&Yhi[(size_t)row * DIM + d4]) = yo;
  }
}

// ---------------------------------------------------------------------------
extern "C" void kernel_launch(void* const* d_in, const int* in_sizes, int n_in,
                              void* d_out, int out_size, void* d_ws,
                              size_t ws_size, hipStream_t stream) {
  const float* x = (const float*)d_in[0];
  const float* norm_w = (const float*)d_in[1];
  const float* in_w = (const float*)d_in[2];
  const float* conv_w = (const float*)d_in[3];
  const float* conv_b = (const float*)d_in[4];
  const float* decay = (const float*)d_in[5];
  const float* gate_w = (const float*)d_in[6];
  const float* out_w = (const float*)d_in[7];
  const float* res_scale = (const float*)d_in[8];
  float* out = (float*)d_out;

  // Workspace layout (bytes), peak 213,909,504 (~204 MiB):
  //  [0,       67.1M)  xb fp32 [M][1024]   (GEMM1a out; phaseA in)
  //  [67.1M,  100.7M)  z  bf16 [M][1024]   (GEMM1z out; phaseC in)
  //  [100.7M, 134.2M)  yhi bf16 [M][1024]  (phaseC out; GEMM2 A)
  //  [134.2M, 201.3M)  xhi|xlo bf16        (GEMM1 A); after GEMM1z dead ->
  //                    hs fp32 [M][1024] overlays it (phaseA out, phaseC in)
  //  [201.3M, 213.9M)  w1hi|w1lo|w2hi|w2lo (bf16, transposed)
  //  fbuf/cbuf (2 MB each) live in d_out scratch (dead until GEMM2 rewrite).
  const size_t NEEDED = 213909504;
  if (ws_size < NEEDED) return;  // clean diagnostic fail instead of OOB fault

  char* w8 = (char*)d_ws;
  float* xb = (float*)(w8);
  unsigned short* zbf = (unsigned short*)(w8 + 67108864);
  unsigned short* yhi = (unsigned short*)(w8 + 100663296);
  unsigned short* xhi = (unsigned short*)(w8 + 134217728);
  unsigned short* xlo = (unsigned short*)(w8 + 167772160);
  float* hs = (float*)(w8 + 134217728);            // overlays xhi/xlo
  unsigned short* w1hi = (unsigned short*)(w8 + 201326592);
  unsigned short* w1lo = (unsigned short*)(w8 + 205520896);
  unsigned short* w2hi = (unsigned short*)(w8 + 209715200);
  unsigned short* w2lo = (unsigned short*)(w8 + 211812352);
  float* fbuf = (float*)d_out;                     // scratch until GEMM2
  float* cbuf = fbuf + (size_t)BATCH * NCHUNK * DIM;

  // 1. fused RMSNorm + bf16 split of x (wave per row)
  splitx_kernel<<<MROWS / 4, 256, 0, stream>>>(x, norm_w, xhi, xlo);

  // 2. both weight transpose+splits in one launch
  splitw2_kernel<<<dim3(64, 32, 2), 256, 0, stream>>>(
      in_w, w1hi, w1lo, out_w, w2hi, w2lo);

  // 3. GEMM1a (bf16x3): xb = norm(x) @ in_w[:, :1024]   fp32 out
  gemm_kernel<4, false, false><<<dim3(8, 128), 256, 0, stream>>>(
      xhi, xlo, w1hi, w1lo, xb, nullptr, DIM, 1024, nullptr, nullptr);

  // 4. GEMM1z (bf16x1): z = norm(x) @ in_w[:, 1024:]    bf16 out
  gemm_kernel<2, false, true><<<dim3(8, 128), 256, 0, stream>>>(
      xhi, nullptr, w1hi + (size_t)1024 * 1024, nullptr, nullptr, zbf,
      DIM, 1024, nullptr, nullptr);

  // 5. conv + silu + local scan (writes hs over dead xhi/xlo)
  phaseA_kernel<<<dim3(DIM / 256, NCHUNK, BATCH), 256, 0, stream>>>(
      xb, conv_w, conv_b, decay, hs, fbuf);

  // 6. chunk carry propagation (prefetch-8 pipeline)
  phaseB_kernel<<<dim3(DIM / 256, BATCH), 256, 0, stream>>>(decay, fbuf, cbuf);

  // 7. carry injection + gated rmsnorm * silu(z) -> yhi (bf16)
  phaseC_kernel<<<MROWS / 4, 256, 0, stream>>>(zbf, hs, cbuf, decay, gate_w, yhi);

  // 8. GEMM2 (bf16x1): out = x * res_scale + y @ out_w
  gemm_kernel<2, true, false><<<dim3(8, 128), 256, 0, stream>>>(
      yhi, nullptr, w2hi, nullptr, out, nullptr, DIM, 1024, x, res_scale);
}